// Round 6
// baseline (154.469 us; speedup 1.0000x reference)
//
#include <hip/hip_runtime.h>
#include <stdint.h>
#include <math.h>

#define NTOT (9*128*128)         // 147456
#define PRE_N 6000
#define POST_N 300
#define CAND_CAP 8192
#define NWORDS 94                // ceil(6000/64)
#define RT 256                   // rank-kernel threads
#define RTILE 2048               // rank-kernel LDS tile (keys)

typedef unsigned long long u64;

// ---- ws layout (bytes) ----
constexpr size_t OFF_META = 0;                            // 64 B (meta[2]=cand counter)
constexpr size_t OFF_CAND = 64;                           // u64*CAND_CAP   = 65536
constexpr size_t OFF_CBOX = OFF_CAND + CAND_CAP*8;        // float4*CAND_CAP= 131072
constexpr size_t OFF_KEY2 = OFF_CBOX + CAND_CAP*16;       // u64*PRE_N      = 48000 (pad 48128)
constexpr size_t OFF_BOXA = OFF_KEY2 + 48128;             // float4*PRE_N   = 96000 (pad 96256)
constexpr size_t OFF_SP   = OFF_BOXA + 96256;             // float4*PRE_N
constexpr size_t OFF_SD   = OFF_SP + 96256;               // float4*PRE_N
constexpr size_t OFF_SUP  = OFF_SD + 96256;               // u64*PRE_N*NWORDS = 4512000

// monotone float -> uint (ascending order preserved, total order)
static __device__ __forceinline__ unsigned int ford(float f) {
    unsigned int b = __float_as_uint(f);
    return b ^ ((b & 0x80000000u) ? 0xFFFFFFFFu : 0x80000000u);
}

__global__ void k_boxes(const float* __restrict__ scores,
                        const float* __restrict__ deltas,
                        const float* __restrict__ anchors,
                        u64* __restrict__ cand,
                        float4* __restrict__ cbox,
                        unsigned int* __restrict__ cnt) {
    int i = blockIdx.x * blockDim.x + threadIdx.x;
    if (i >= NTOT) return;
    int a   = i >> 14;
    int rem = i & 16383;
    float4 d  = ((const float4*)deltas)[a * 16384 + rem]; // raw-reshape layout
    float4 an = ((const float4*)anchors)[i];
    float x1 = fmaxf(an.x + d.x, 0.0f);
    float y1 = fmaxf(an.y + d.y, 0.0f);
    float bw = fmaxf(an.z + d.z, 0.0f);
    float bh = fmaxf(an.w + d.w, 0.0f);
    float x2 = fminf(x1 + bw - 1.0f, 127.0f);   // uses pre-clamp x1
    float y2 = fminf(y1 + bh - 1.0f, 127.0f);
    x1 = fminf(x1, 127.0f);
    y1 = fminf(y1, 127.0f);
    bw = x2 - x1 + 1.0f;
    bh = y2 - y1 + 1.0f;
    bool valid = (bw >= 16.0f) && (bh >= 16.0f);
    // Only valid entries can ever reach the output (invalid score = -inf,
    // V=0 downstream). Append order is nondeterministic but ranks are
    // computed from the unique keys -> deterministic final placement.
    if (valid) {
        unsigned int inv = ~ford(scores[i]);    // ascending inv <=> score desc
        u64 key = ((u64)inv << 32) | (unsigned int)i;
        unsigned int p = atomicAdd(cnt, 1u);
        if (p < CAND_CAP) { cand[p] = key; cbox[p] = make_float4(x1, y1, bw, bh); }
    }
}

// rank by score-key (exact: keys unique). rank r = #{keys < mine}.
// r < PRE_N  =>  this is top-k slot r (score desc, idx asc = lax.top_k order).
__global__ void __launch_bounds__(RT)
k_rank1(const u64* __restrict__ cand, const float4* __restrict__ cbox,
        const unsigned int* __restrict__ meta,
        u64* __restrict__ key2, float4* __restrict__ boxA) {
    __shared__ u64 tile[RTILE];
    unsigned int cnt = meta[2];
    if (cnt > CAND_CAP) cnt = CAND_CAP;
    int i = blockIdx.x * RT + threadIdx.x;
    bool act = (i < (int)cnt);
    u64 my = act ? cand[i] : ~0ull;
    int r = 0;
    for (unsigned int base = 0; base < cnt; base += RTILE) {
        unsigned int n = min((unsigned int)RTILE, cnt - base);
        for (unsigned int t = threadIdx.x; t < n; t += RT) tile[t] = cand[base + t];
        __syncthreads();
        if (act) {
            unsigned int t = 0;
            for (; t + 4 <= n; t += 4) {
                r += (tile[t]   < my);
                r += (tile[t+1] < my);
                r += (tile[t+2] < my);
                r += (tile[t+3] < my);
            }
            for (; t < n; ++t) r += (tile[t] < my);
        }
        __syncthreads();
    }
    if (act && r < PRE_N) {
        float4 b = cbox[i];
        float py2 = (b.y + b.w) - 1.0f;
        key2[r] = ((u64)(~ford(py2)) << 32) | (u64)r;   // (py2 desc, stable by rank)
        boxA[r] = b;
    }
}

// rank by py2-key among the top nreal; scatter boxes into final NMS order.
__global__ void __launch_bounds__(RT)
k_rank2(const u64* __restrict__ key2, const float4* __restrict__ boxA,
        const unsigned int* __restrict__ meta,
        float4* __restrict__ sP, float4* __restrict__ sD) {
    __shared__ u64 tile[RTILE];
    unsigned int cnt = meta[2];
    if (cnt > CAND_CAP) cnt = CAND_CAP;
    unsigned int nreal = (cnt < PRE_N) ? cnt : PRE_N;
    int i = blockIdx.x * RT + threadIdx.x;    // i = top-k rank r1
    bool act = (i < (int)nreal);
    u64 my = act ? key2[i] : ~0ull;
    int r = 0;
    for (unsigned int base = 0; base < nreal; base += RTILE) {
        unsigned int n = min((unsigned int)RTILE, nreal - base);
        for (unsigned int t = threadIdx.x; t < n; t += RT) tile[t] = key2[base + t];
        __syncthreads();
        if (act) {
            unsigned int t = 0;
            for (; t + 4 <= n; t += 4) {
                r += (tile[t]   < my);
                r += (tile[t+1] < my);
                r += (tile[t+2] < my);
                r += (tile[t+3] < my);
            }
            for (; t < n; ++t) r += (tile[t] < my);
        }
        __syncthreads();
    }
    if (act) {
        float4 b = boxA[i];
        float px2  = (b.x + b.z) - 1.0f;
        float py2s = (b.y + b.w) - 1.0f;
        float area = b.z * b.w;
        sP[r] = b;
        sD[r] = make_float4(px2, py2s, area, 1.0f);
    }
}

__global__ void k_sup(const float4* __restrict__ sP,
                      const float4* __restrict__ sD,
                      const unsigned int* __restrict__ meta,
                      u64* __restrict__ sup) {
    unsigned int cnt = meta[2];
    if (cnt > CAND_CAP) cnt = CAND_CAP;
    int nreal = (cnt < PRE_N) ? (int)cnt : PRE_N;
    int wreal = (nreal + 63) >> 6;
    int t = blockIdx.x * blockDim.x + threadIdx.x;
    if (t >= PRE_N * NWORDS) return;
    int i = t % PRE_N;           // consecutive lanes -> consecutive i (coalesced)
    int w = t / PRE_N;
    if (i >= nreal || w >= wreal) return;
    float4 p  = sP[i];
    float4 dI = sD[i];
    u64 bits = 0;
    int jbase = w * 64;
    int jend  = min(jbase + 64, nreal);
    for (int j = max(jbase, i + 1); j < jend; ++j) {
        float4 q  = sP[j];
        float4 dJ = sD[j];
        float iw = fmaxf(fminf(dI.x, dJ.x) - fmaxf(p.x, q.x) + 1.0f, 0.0f);
        float ih = fmaxf(fminf(dI.y, dJ.y) - fmaxf(p.y, q.y) + 1.0f, 0.0f);
        if (iw * ih >= 0.7f * dJ.z) bits |= 1ull << (j - jbase);
    }
    sup[(size_t)i * NWORDS + w] = bits;
}

// Block-resolve greedy NMS scan: per 64-candidate block, one parallel column
// load resolves intra-block suppression in registers; keep rows are OR'd into
// the removed-mask with all loads issued before a single wait.
__global__ void k_scan(const float4* __restrict__ sP,
                       const u64* __restrict__ sup,
                       const unsigned int* __restrict__ meta,
                       float4* __restrict__ out) {
    __shared__ int keepj[POST_N];
    int lane = threadIdx.x;   // single wave of 64
    unsigned int cnt = meta[2];
    if (cnt > CAND_CAP) cnt = CAND_CAP;
    int nreal = (cnt < PRE_N) ? (int)cnt : PRE_N;
    int nblk = (nreal + 63) >> 6;
    int wreal = nblk;
    u64 rem0 = 0, rem1 = 0;   // removed-mask: lane l holds words l, l+64
    int kept = 0;

    // prefetch column word for block 0: word 0 of rows 0..63
    u64 colv = 0;
    if (lane < nreal) colv = sup[(size_t)lane * NWORDS + 0];

    for (int w = 0; w < nblk; ++w) {
        // prefetch next block's column (independent, overlaps this block)
        u64 colnext = 0;
        int jn = (w + 1) * 64 + lane;
        if (w + 1 < nblk && jn < nreal) colnext = sup[(size_t)jn * NWORDS + (w + 1)];

        int rembits = nreal - w * 64;
        u64 vmw = (rembits >= 64) ? ~0ull : ((1ull << rembits) - 1ull);
        u64 remw = (w < 64) ? __shfl(rem0, w) : __shfl(rem1, w - 64);
        u64 live = vmw & ~remw;
        if (live) {
            // intra-block greedy resolve (registers + shfl only)
            u64 keeps_mask = 0;
            bool full = false;
            while (live) {
                int b = __ffsll(live) - 1;
                keeps_mask |= 1ull << b;
                if (lane == 0) keepj[kept] = w * 64 + b;
                kept++;
                if (kept >= POST_N) { full = true; break; }
                live &= ~(1ull << b);
                live &= ~__shfl(colv, b);   // bits of this block suppressed by b
            }
            if (full) break;
            // cross-block: OR keep rows into rem; batch up to 16 loads per wait
            u64 km = keeps_mask;
            while (km) {
                int b0=-1,b1=-1,b2=-1,b3=-1,b4=-1,b5=-1,b6=-1,b7=-1;
                int b8=-1,b9=-1,b10=-1,b11=-1,b12=-1,b13=-1,b14=-1,b15=-1;
#define EXTR(bn) if (km) { bn = __ffsll(km) - 1; km &= km - 1; }
                EXTR(b0) EXTR(b1) EXTR(b2) EXTR(b3) EXTR(b4) EXTR(b5) EXTR(b6) EXTR(b7)
                EXTR(b8) EXTR(b9) EXTR(b10) EXTR(b11) EXTR(b12) EXTR(b13) EXTR(b14) EXTR(b15)
#undef EXTR
                u64 o0=0,o1=0,o2=0,o3=0,o4=0,o5=0,o6=0,o7=0;
                u64 o8=0,o9=0,o10=0,o11=0,o12=0,o13=0,o14=0,o15=0;
                if (lane < wreal) {
                    size_t rb = (size_t)(w * 64) * NWORDS + lane;
#define LD(on,bn) if (bn >= 0) on = sup[rb + (size_t)bn * NWORDS];
                    LD(o0,b0) LD(o1,b1) LD(o2,b2) LD(o3,b3)
                    LD(o4,b4) LD(o5,b5) LD(o6,b6) LD(o7,b7)
                    LD(o8,b8) LD(o9,b9) LD(o10,b10) LD(o11,b11)
                    LD(o12,b12) LD(o13,b13) LD(o14,b14) LD(o15,b15)
#undef LD
                }
                rem0 |= (o0|o1|o2|o3|o4|o5|o6|o7|o8|o9|o10|o11|o12|o13|o14|o15);
                if (64 + lane < wreal) {     // only when >4096 candidates
                    size_t rb = (size_t)(w * 64) * NWORDS + 64 + lane;
                    u64 q = 0;
#define LD2(bn) if (bn >= 0) q |= sup[rb + (size_t)bn * NWORDS];
                    LD2(b0) LD2(b1) LD2(b2) LD2(b3) LD2(b4) LD2(b5) LD2(b6) LD2(b7)
                    LD2(b8) LD2(b9) LD2(b10) LD2(b11) LD2(b12) LD2(b13) LD2(b14) LD2(b15)
#undef LD2
                    rem1 |= q;
                }
            }
        }
        colv = colnext;
    }
    // parallel output phase: gather kept boxes, zero-fill the rest
    __syncthreads();
    for (int r = lane; r < POST_N; r += 64) {
        float4 v = make_float4(0.f, 0.f, 0.f, 0.f);
        if (r < kept) v = sP[keepj[r]];
        out[r] = v;
    }
}

extern "C" void kernel_launch(void* const* d_in, const int* in_sizes, int n_in,
                              void* d_out, int out_size, void* d_ws, size_t ws_size,
                              hipStream_t stream) {
    const float* scores  = (const float*)d_in[0];
    const float* deltas  = (const float*)d_in[1];
    const float* anchors = (const float*)d_in[2];
    char* ws = (char*)d_ws;

    unsigned int* meta = (unsigned int*)(ws + OFF_META);
    u64*          cand = (u64*)(ws + OFF_CAND);
    float4*       cbox = (float4*)(ws + OFF_CBOX);
    u64*          key2 = (u64*)(ws + OFF_KEY2);
    float4*       boxA = (float4*)(ws + OFF_BOXA);
    float4*       sP   = (float4*)(ws + OFF_SP);
    float4*       sD   = (float4*)(ws + OFF_SD);
    u64*          sup  = (u64*)(ws + OFF_SUP);

    hipMemsetAsync(ws + OFF_META, 0, 64, stream);   // zero cand counter

    k_boxes<<<(NTOT + 255) / 256, 256, 0, stream>>>(scores, deltas, anchors,
                                                    cand, cbox, &meta[2]);
    k_rank1<<<CAND_CAP / RT, RT, 0, stream>>>(cand, cbox, meta, key2, boxA);
    k_rank2<<<(PRE_N + RT - 1) / RT, RT, 0, stream>>>(key2, boxA, meta, sP, sD);
    k_sup<<<(PRE_N * NWORDS + 255) / 256, 256, 0, stream>>>(sP, sD, meta, sup);
    k_scan<<<1, 64, 0, stream>>>(sP, sup, meta, (float4*)d_out);
}